// Round 1
// baseline (150.983 us; speedup 1.0000x reference)
//
#include <hip/hip_runtime.h>

typedef unsigned short u16;
typedef unsigned int u32;
using short8 = __attribute__((ext_vector_type(8))) short;
using f32x4  = __attribute__((ext_vector_type(4))) float;

#define NB 8
#define NN 2048
#define ND 64
#define NCHUNK 4
#define JCHUNK (NN / NCHUNK)   // 512

__device__ __forceinline__ u16 f2bf(float f) {
    u32 u = __float_as_uint(f);
    u32 r = (u + 0x7fffu + ((u >> 16) & 1u)) >> 16;   // RNE to bf16
    return (u16)r;
}
__device__ __forceinline__ float bf2f(u16 h) {
    return __uint_as_float(((u32)h) << 16);
}
// order-preserving float<->uint encoding for atomicMax
__device__ __forceinline__ u32 encf(float f) {
    u32 u = __float_as_uint(f);
    return (u & 0x80000000u) ? ~u : (u | 0x80000000u);
}
__device__ __forceinline__ float decf(u32 u) {
    return __uint_as_float((u & 0x80000000u) ? (u & 0x7fffffffu) : ~u);
}

// K1: h = x @ W ; es = h@a_src ; ed = h@a_dst ; per-batch max(ed) ;
// hT_hi/hT_lo: bf16 split of h, TRANSPOSED [b][d][n]
__global__ __launch_bounds__(256) void gat_k1(
    const float* __restrict__ x, const float* __restrict__ W, const float* __restrict__ a,
    u16* __restrict__ hT_hi, u16* __restrict__ hT_lo,
    float* __restrict__ es, float* __restrict__ ed, u32* __restrict__ edmax)
{
    const int tid  = threadIdx.x;
    const int lane = tid & 63;
    const int wid  = __builtin_amdgcn_readfirstlane(tid >> 6);
    const int rowbase = blockIdx.x * 16;          // global row in [0, B*N)
    const int row0 = rowbase + wid * 4;
    const int b    = rowbase >> 11;
    const int col0 = rowbase & 2047;

    float Wc[64];
#pragma unroll
    for (int k = 0; k < 64; ++k) Wc[k] = W[k * 64 + lane];
    const float asrc = a[lane], adst = a[64 + lane];

    __shared__ u16 lh[64][20];   // +4 pad: bank spread, keeps 8B alignment
    __shared__ u16 ll[64][20];

    float edm = -1e30f;
#pragma unroll
    for (int r = 0; r < 4; ++r) {
        const float* xr = x + (size_t)(row0 + r) * 64;  // wave-uniform -> s_load
        float acc = 0.f;
#pragma unroll
        for (int k = 0; k < 64; ++k) acc = fmaf(xr[k], Wc[k], acc);
        float vs = acc * asrc, vd = acc * adst;
#pragma unroll
        for (int off = 32; off; off >>= 1) {
            vs += __shfl_xor(vs, off, 64);
            vd += __shfl_xor(vd, off, 64);
        }
        if (lane == 0) { es[row0 + r] = vs; ed[row0 + r] = vd; }
        edm = fmaxf(edm, vd);
        u16 hi = f2bf(acc);
        float lo = acc - bf2f(hi);
        lh[lane][wid * 4 + r] = hi;
        ll[lane][wid * 4 + r] = f2bf(lo);
    }
    if (lane == 0) atomicMax(edmax + b, encf(edm));
    __syncthreads();

    // transposed write-out: thread t -> d = t>>2, j-part = t&3 (4 bf16 = 8B)
    const int d = tid >> 2, part = tid & 3;
    u32 h0 = lh[d][part*4+0] | ((u32)lh[d][part*4+1] << 16);
    u32 h1 = lh[d][part*4+2] | ((u32)lh[d][part*4+3] << 16);
    u32 l0 = ll[d][part*4+0] | ((u32)ll[d][part*4+1] << 16);
    u32 l1 = ll[d][part*4+2] | ((u32)ll[d][part*4+3] << 16);
    size_t goff = (size_t)(b * 64 + d) * 2048 + col0 + part * 4;
    *reinterpret_cast<uint2*>(hT_hi + goff) = make_uint2(h0, h1);
    *reinterpret_cast<uint2*>(hT_lo + goff) = make_uint2(l0, l1);
}

// K3: fused masked-softmax + PV via MFMA. One wave = 16 i-rows, j-chunk sweep.
__global__ __launch_bounds__(256, 4) void gat_k3(
    const int* __restrict__ adj,
    const u16* __restrict__ hT_hi, const u16* __restrict__ hT_lo,
    const float* __restrict__ es, const float* __restrict__ ed,
    const u32* __restrict__ edmax,
    float* __restrict__ acc_part, float* __restrict__ s_part)
{
    const int g = blockIdx.x;
    const int b = g & 7;                  // batch = g%8 -> pins batch to XCD
    const int rest  = g >> 3;
    const int itile = rest & 31;          // 32 i-tiles of 64 rows
    const int chunk = rest >> 5;          // 4 j-chunks
    const int tid  = threadIdx.x;
    const int lane = tid & 63;
    const int wid  = tid >> 6;
    const int li   = lane & 15;           // A-frag row / B-frag col / C col
    const int lg   = lane >> 4;           // k-group
    const int i0   = itile * 64 + wid * 16;

    const float es_i = es[b * 2048 + i0 + li];
    const float edM  = decf(edmax[b]);
    const float t0   = es_i + edM;
    const float Mi   = fmaxf(t0, 0.2f * t0);     // exact upper bound on row max
    const float L2E  = 1.44269504088896f;
    const float CL   = Mi * L2E;

    const int*   __restrict__ arow = adj + ((size_t)(b * 2048 + i0 + li)) * 2048;
    const float* __restrict__ edb  = ed + b * 2048;
    const u16*   __restrict__ bh   = hT_hi + (size_t)(b * 64 + li) * 2048;
    const u16*   __restrict__ bl   = hT_lo + (size_t)(b * 64 + li) * 2048;

    f32x4 acc0 = {0.f,0.f,0.f,0.f}, acc1 = {0.f,0.f,0.f,0.f};
    f32x4 acc2 = {0.f,0.f,0.f,0.f}, acc3 = {0.f,0.f,0.f,0.f};
    float rs = 0.f;

    const int jstart = chunk * JCHUNK;
    for (int kk = 0; kk < JCHUNK / 32; ++kk) {
        const int jb = jstart + kk * 32 + lg * 8;
        const int4   a0 = *reinterpret_cast<const int4*>(arow + jb);
        const int4   a1 = *reinterpret_cast<const int4*>(arow + jb + 4);
        const float4 e0 = *reinterpret_cast<const float4*>(edb + jb);
        const float4 e1 = *reinterpret_cast<const float4*>(edb + jb + 4);

        float pe[8];
        {
            float tt, eL;
            tt = es_i + e0.x; eL = fmaxf(tt, 0.2f*tt); pe[0] = a0.x ? __builtin_amdgcn_exp2f(fmaf(eL, L2E, -CL)) : 0.f;
            tt = es_i + e0.y; eL = fmaxf(tt, 0.2f*tt); pe[1] = a0.y ? __builtin_amdgcn_exp2f(fmaf(eL, L2E, -CL)) : 0.f;
            tt = es_i + e0.z; eL = fmaxf(tt, 0.2f*tt); pe[2] = a0.z ? __builtin_amdgcn_exp2f(fmaf(eL, L2E, -CL)) : 0.f;
            tt = es_i + e0.w; eL = fmaxf(tt, 0.2f*tt); pe[3] = a0.w ? __builtin_amdgcn_exp2f(fmaf(eL, L2E, -CL)) : 0.f;
            tt = es_i + e1.x; eL = fmaxf(tt, 0.2f*tt); pe[4] = a1.x ? __builtin_amdgcn_exp2f(fmaf(eL, L2E, -CL)) : 0.f;
            tt = es_i + e1.y; eL = fmaxf(tt, 0.2f*tt); pe[5] = a1.y ? __builtin_amdgcn_exp2f(fmaf(eL, L2E, -CL)) : 0.f;
            tt = es_i + e1.z; eL = fmaxf(tt, 0.2f*tt); pe[6] = a1.z ? __builtin_amdgcn_exp2f(fmaf(eL, L2E, -CL)) : 0.f;
            tt = es_i + e1.w; eL = fmaxf(tt, 0.2f*tt); pe[7] = a1.w ? __builtin_amdgcn_exp2f(fmaf(eL, L2E, -CL)) : 0.f;
        }
        rs += ((pe[0]+pe[1]) + (pe[2]+pe[3])) + ((pe[4]+pe[5]) + (pe[6]+pe[7]));

        short8 pa;
#pragma unroll
        for (int q = 0; q < 8; ++q) pa[q] = (short)f2bf(pe[q]);

        // B frags: 8 consecutive j (bf16) at fixed d = dt*16 + li
        short8 b0h = *reinterpret_cast<const short8*>(bh + (size_t)0*16*2048 + jb);
        short8 b1h = *reinterpret_cast<const short8*>(bh + (size_t)1*16*2048 + jb);
        short8 b2h = *reinterpret_cast<const short8*>(bh + (size_t)2*16*2048 + jb);
        short8 b3h = *reinterpret_cast<const short8*>(bh + (size_t)3*16*2048 + jb);
        short8 b0l = *reinterpret_cast<const short8*>(bl + (size_t)0*16*2048 + jb);
        short8 b1l = *reinterpret_cast<const short8*>(bl + (size_t)1*16*2048 + jb);
        short8 b2l = *reinterpret_cast<const short8*>(bl + (size_t)2*16*2048 + jb);
        short8 b3l = *reinterpret_cast<const short8*>(bl + (size_t)3*16*2048 + jb);

        acc0 = __builtin_amdgcn_mfma_f32_16x16x32_bf16(pa, b0h, acc0, 0, 0, 0);
        acc1 = __builtin_amdgcn_mfma_f32_16x16x32_bf16(pa, b1h, acc1, 0, 0, 0);
        acc2 = __builtin_amdgcn_mfma_f32_16x16x32_bf16(pa, b2h, acc2, 0, 0, 0);
        acc3 = __builtin_amdgcn_mfma_f32_16x16x32_bf16(pa, b3h, acc3, 0, 0, 0);
        acc0 = __builtin_amdgcn_mfma_f32_16x16x32_bf16(pa, b0l, acc0, 0, 0, 0);
        acc1 = __builtin_amdgcn_mfma_f32_16x16x32_bf16(pa, b1l, acc1, 0, 0, 0);
        acc2 = __builtin_amdgcn_mfma_f32_16x16x32_bf16(pa, b2l, acc2, 0, 0, 0);
        acc3 = __builtin_amdgcn_mfma_f32_16x16x32_bf16(pa, b3l, acc3, 0, 0, 0);
    }

    // full row-sum: combine the 4 k-groups (lanes with same li)
    rs += __shfl_xor(rs, 16, 64);
    rs += __shfl_xor(rs, 32, 64);
    if (lane < 16)
        s_part[(size_t)chunk * (NB*NN) + b * 2048 + i0 + li] = rs;

    // C layout: row = 4*lg + r, col = li
    float* ap = acc_part + ((size_t)chunk * (NB*NN) + b * 2048 + i0) * 64;
    f32x4 accs[4] = {acc0, acc1, acc2, acc3};
#pragma unroll
    for (int dt = 0; dt < 4; ++dt) {
#pragma unroll
        for (int r = 0; r < 4; ++r) {
            ap[(size_t)(4 * lg + r) * 64 + dt * 16 + li] = accs[dt][r];
        }
    }
}

// K4: combine j-chunks, normalize
__global__ __launch_bounds__(256) void gat_k4(
    const float* __restrict__ acc_part, const float* __restrict__ s_part,
    float* __restrict__ out)
{
    const int tid = threadIdx.x;
    const int row = blockIdx.x * 4 + (tid >> 6);
    const int d   = tid & 63;
    const size_t idx = (size_t)row * 64 + d;
    float sum = 0.f, st = 0.f;
#pragma unroll
    for (int c = 0; c < NCHUNK; ++c) sum += acc_part[(size_t)c * (NB*NN) * 64 + idx];
#pragma unroll
    for (int c = 0; c < NCHUNK; ++c) st  += s_part[(size_t)c * (NB*NN) + row];
    out[idx] = sum / st;
}

extern "C" void kernel_launch(void* const* d_in, const int* in_sizes, int n_in,
                              void* d_out, int out_size, void* d_ws, size_t ws_size,
                              hipStream_t stream)
{
    const float* x   = (const float*)d_in[0];
    const int*   adj = (const int*)d_in[1];
    const float* W   = (const float*)d_in[2];
    const float* a   = (const float*)d_in[3];
    float* out = (float*)d_out;

    // workspace carve (needs ~21.5 MB)
    char* ws = (char*)d_ws;
    size_t off = 0;
    auto carve = [&](size_t bytes) -> void* {
        void* p = ws + off;
        off += (bytes + 255) & ~(size_t)255;
        return p;
    };
    u16*   hT_hi    = (u16*)  carve((size_t)NB * 64 * NN * 2);
    u16*   hT_lo    = (u16*)  carve((size_t)NB * 64 * NN * 2);
    float* es       = (float*)carve((size_t)NB * NN * 4);
    float* ed       = (float*)carve((size_t)NB * NN * 4);
    u32*   edmax    = (u32*)  carve(256);
    float* s_part   = (float*)carve((size_t)NCHUNK * NB * NN * 4);
    float* acc_part = (float*)carve((size_t)NCHUNK * NB * NN * 64 * 4);
    (void)ws_size; (void)in_sizes; (void)n_in; (void)out_size;

    hipMemsetAsync(edmax, 0, 256, stream);
    gat_k1<<<NB * NN / 16, 256, 0, stream>>>(x, W, a, hT_hi, hT_lo, es, ed, edmax);
    gat_k3<<<NCHUNK * (NB * NN / 64), 256, 0, stream>>>(adj, hT_hi, hT_lo, es, ed, edmax,
                                                        acc_part, s_part);
    gat_k4<<<NB * NN / 4, 256, 0, stream>>>(acc_part, s_part, out);
}